// Round 1
// baseline (120.552 us; speedup 1.0000x reference)
//
#include <hip/hip_runtime.h>
#include <math.h>

#define S 1024
#define C 4096
#define K 4

__device__ __forceinline__ float softplusf(float x) {
    // log(1+exp(x)), stable
    return fmaxf(x, 0.0f) + log1pf(expf(-fabsf(x)));
}
__device__ __forceinline__ float logaddexpf_(float a, float b) {
    float mx = fmaxf(a, b), mn = fminf(a, b);
    return mx + log1pf(expf(mn - mx));
}

// ---------------------------------------------------------------------------
// Kernel 1: per-row j of Recipients_mat:
//   cnt[j]  = max(sum_k R[j][k], 1)
//   Ebar[j] = (sum_k R[j][k]*E[k]) / cnt[j]
//   E_new[j] = pL + pD*E[j]^2 + pT*E[j]*Ebar[j] + pS*E[sC1[j]]*E[sC2[j]]
//   logE[j] = log(E_new[j]);  logCnt[j] = log(cnt[j])
// grid = S blocks x 256 threads (coalesced row reads)
// ---------------------------------------------------------------------------
__global__ __launch_bounds__(256) void k_ebar(
    const float* __restrict__ E, const float* __restrict__ Recip,
    const int* __restrict__ sC1, const int* __restrict__ sC2,
    const float* __restrict__ ld, const float* __restrict__ lt,
    const float* __restrict__ ll,
    float* __restrict__ logE, float* __restrict__ logCnt) {
    __shared__ float sc[256], sd[256];
    int j = blockIdx.x;
    int t = threadIdx.x;
    const float* row = Recip + (size_t)j * S;
    float c = 0.f, d = 0.f;
    for (int k = t; k < S; k += 256) {
        float r = row[k];
        c += r;
        d += r * E[k];
    }
    sc[t] = c; sd[t] = d;
    __syncthreads();
    for (int o = 128; o > 0; o >>= 1) {
        if (t < o) { sc[t] += sc[t + o]; sd[t] += sd[t + o]; }
        __syncthreads();
    }
    if (t == 0) {
        float cnt  = fmaxf(sc[0], 1.0f);
        float ebar = sd[0] / cnt;
        float delta = softplusf(ld[0]);
        float tau   = softplusf(lt[0]);
        float lam   = softplusf(ll[0]);
        float rs = 1.0f + delta + tau + lam;
        float pS = 1.0f / rs, pD = delta / rs, pT = tau / rs, pL = lam / rs;
        float Ej = E[j];
        float en = pL + pD * Ej * Ej + pT * Ej * ebar + pS * E[sC1[j]] * E[sC2[j]];
        logE[j]   = logf(en);
        logCnt[j] = logf(cnt);
    }
}

// ---------------------------------------------------------------------------
// Kernel 2: for each of 8 slots (4 A-rows from splits_c1[root], 4 B-rows from
// splits_c2[root]): m[slot] = max_k log_Pi[row][k]; w[slot][k] = exp(lp - m)
// grid = 8 blocks x 1024 threads
// ---------------------------------------------------------------------------
__global__ __launch_bounds__(1024) void k_wrow(
    const float* __restrict__ logPi, const int* __restrict__ sp1,
    const int* __restrict__ sp2, const int* __restrict__ rootp,
    float* __restrict__ wrows, float* __restrict__ mvals) {
    __shared__ float sm[1024];
    int slot = blockIdx.x;   // 0..7
    int t = threadIdx.x;     // 0..1023
    int root = rootp[0];
    int row = (slot < K) ? sp1[root * K + slot] : sp2[root * K + (slot - K)];
    float v = logPi[(size_t)row * S + t];
    sm[t] = v;
    __syncthreads();
    for (int o = 512; o > 0; o >>= 1) {
        if (t < o) sm[t] = fmaxf(sm[t], sm[t + o]);
        __syncthreads();
    }
    float m = sm[0];
    wrows[slot * S + t] = expf(v - m);
    if (t == 0) mvals[slot] = m;
}

// ---------------------------------------------------------------------------
// Kernel 3: sums[slot][j] = sum_k Recip[j][k] * w[slot][k]
//   logTbar[slot][j] = log(max(sums,1e-30)) - logCnt[j] + m[slot]
// grid = (S, 8) blocks x 256 threads
// ---------------------------------------------------------------------------
__global__ __launch_bounds__(256) void k_sums(
    const float* __restrict__ Recip, const float* __restrict__ wrows,
    const float* __restrict__ mvals, const float* __restrict__ logCnt,
    float* __restrict__ logTbar) {
    __shared__ float sa[256];
    int j = blockIdx.x, slot = blockIdx.y, t = threadIdx.x;
    const float* row = Recip + (size_t)j * S;
    const float* w = wrows + slot * S;
    float acc = 0.f;
    for (int k = t; k < S; k += 256) acc += row[k] * w[k];
    sa[t] = acc;
    __syncthreads();
    for (int o = 128; o > 0; o >>= 1) {
        if (t < o) sa[t] += sa[t + o];
        __syncthreads();
    }
    if (t == 0)
        logTbar[slot * S + j] = logf(fmaxf(sa[0], 1e-30f)) - logCnt[j] + mvals[slot];
}

// ---------------------------------------------------------------------------
// Kernel 4: for the single root row, per column j compute
//   spec, dup, trans, sl  -> combined[j];  out = logsumexp_j(leaf ? lp : comb)
// 1 block x 1024 threads
// ---------------------------------------------------------------------------
__global__ __launch_bounds__(1024) void k_final(
    const float* __restrict__ logPi, const int* __restrict__ sC1,
    const int* __restrict__ sC2, const int* __restrict__ sp1,
    const int* __restrict__ sp2, const float* __restrict__ logq,
    const void* __restrict__ isLeaf, const int* __restrict__ rootp,
    const float* __restrict__ ld, const float* __restrict__ lt,
    const float* __restrict__ ll,
    const float* __restrict__ logE, const float* __restrict__ logTbar,
    float* __restrict__ out) {
    __shared__ float sA[8][S];   // A rows (slots 0..3) and B rows (4..7): 32 KB
    __shared__ float sLogE[S];   // 4 KB
    __shared__ float sRoot[S];   // 4 KB
    __shared__ float red[1024];  // 4 KB
    int t = threadIdx.x;
    int root = rootp[0];

    for (int slot = 0; slot < 8; ++slot) {
        int row = (slot < K) ? sp1[root * K + slot] : sp2[root * K + (slot - K)];
        sA[slot][t] = logPi[(size_t)row * S + t];
    }
    sLogE[t] = logE[t];
    sRoot[t] = logPi[(size_t)root * S + t];
    __syncthreads();

    float delta = softplusf(ld[0]);
    float tau   = softplusf(lt[0]);
    float lam   = softplusf(ll[0]);
    float rs = 1.0f + delta + tau + lam;
    float lpS = logf(1.0f / rs), lpD = logf(delta / rs), lpT = logf(tau / rs);

    int j = t;
    int f = sC1[j], g = sC2[j];

    float vs[K], vd[K], vt[K];
    float ms = -INFINITY, md = -INFINITY, mt = -INFINITY;
    for (int k = 0; k < K; ++k) {
        float lq = logq[root * K + k];
        float Aj = sA[k][j],     Bj = sA[4 + k][j];
        float Af = sA[k][f],     Ag = sA[k][g];
        float Bf = sA[4 + k][f], Bg = sA[4 + k][g];
        vs[k] = lq + logaddexpf_(Af + Bg, Ag + Bf);
        vd[k] = lq + Aj + Bj;
        float TbAj = logTbar[k * S + j];
        float TbBj = logTbar[(4 + k) * S + j];
        vt[k] = lq + logaddexpf_(Aj + TbBj, Bj + TbAj);
        ms = fmaxf(ms, vs[k]); md = fmaxf(md, vd[k]); mt = fmaxf(mt, vt[k]);
    }
    float ss = 0.f, sd_ = 0.f, st = 0.f;
    for (int k = 0; k < K; ++k) {
        ss  += expf(vs[k] - ms);
        sd_ += expf(vd[k] - md);
        st  += expf(vt[k] - mt);
    }
    float vspec  = lpS + ms + logf(ss);
    float vdup   = lpD + md + logf(sd_);
    float vtrans = lpT + mt + logf(st);
    float vsl = lpS + logaddexpf_(sRoot[f] + sLogE[g], sRoot[g] + sLogE[f]);

    float cm = fmaxf(fmaxf(vspec, vdup), fmaxf(vtrans, vsl));
    float comb = cm + logf(expf(vspec - cm) + expf(vdup - cm) +
                           expf(vtrans - cm) + expf(vsl - cm));

    // is_leaf[root]: layout-agnostic read (exact for root==0 under byte-bool,
    // int32, or float32 storage of the bool array).
    unsigned int u = ((const unsigned int*)isLeaf)[root];
    bool leaf = ((u & 0xFFu) != 0u) || (u == 0x3F800000u);

    float x = leaf ? sRoot[j] : comb;

    // block-wide logsumexp over 1024 values
    red[t] = x;
    __syncthreads();
    for (int o = 512; o > 0; o >>= 1) {
        if (t < o) red[t] = fmaxf(red[t], red[t + o]);
        __syncthreads();
    }
    float m = red[0];
    __syncthreads();
    red[t] = expf(x - m);
    __syncthreads();
    for (int o = 512; o > 0; o >>= 1) {
        if (t < o) red[t] += red[t + o];
        __syncthreads();
    }
    if (t == 0) out[0] = m + logf(red[0]);
}

extern "C" void kernel_launch(void* const* d_in, const int* in_sizes, int n_in,
                              void* d_out, int out_size, void* d_ws, size_t ws_size,
                              hipStream_t stream) {
    const float* log_delta = (const float*)d_in[0];
    const float* log_tau   = (const float*)d_in[1];
    const float* log_lambda= (const float*)d_in[2];
    const float* E         = (const float*)d_in[3];
    const float* log_Pi    = (const float*)d_in[4];
    const int*   s_C1      = (const int*)d_in[5];
    const int*   s_C2      = (const int*)d_in[6];
    const float* Recip     = (const float*)d_in[7];
    const int*   splits_c1 = (const int*)d_in[8];
    const int*   splits_c2 = (const int*)d_in[9];
    const float* log_q     = (const float*)d_in[10];
    const void*  is_leaf   = (const void*)d_in[11];
    const int*   root_id   = (const int*)d_in[12];
    float* out = (float*)d_out;

    float* ws      = (float*)d_ws;
    float* logE    = ws;                 // S
    float* logCnt  = ws + S;             // S
    float* wrows   = ws + 2 * S;         // 8*S
    float* mvals   = ws + 10 * S;        // 8
    float* logTbar = ws + 10 * S + 8;    // 8*S

    k_ebar<<<dim3(S), dim3(256), 0, stream>>>(E, Recip, s_C1, s_C2,
                                              log_delta, log_tau, log_lambda,
                                              logE, logCnt);
    k_wrow<<<dim3(8), dim3(1024), 0, stream>>>(log_Pi, splits_c1, splits_c2,
                                               root_id, wrows, mvals);
    k_sums<<<dim3(S, 8), dim3(256), 0, stream>>>(Recip, wrows, mvals, logCnt,
                                                 logTbar);
    k_final<<<dim3(1), dim3(1024), 0, stream>>>(log_Pi, s_C1, s_C2,
                                                splits_c1, splits_c2, log_q,
                                                is_leaf, root_id,
                                                log_delta, log_tau, log_lambda,
                                                logE, logTbar, out);
}